// Round 11
// baseline (40.905 us; speedup 1.0000x reference)
//
#include <hip/hip_runtime.h>

#define H_DIM 3072
#define W_DIM 3072
#define GBX 48    // 3072/64 column blocks
#define GBY 768   // 3072/4  row blocks
#define NBLK (GBX * GBY)   // 36864 = 8 * 4608
#define NXCD 8
#define CHUNK (NBLK / NXCD)  // 4608 = 6 stripes * 768

// 4B-aligned vector types: tap base addrs ((r*W+c)*3 floats) are only 4B-aligned.
typedef float f32x4 __attribute__((ext_vector_type(4)));
typedef float f32x2 __attribute__((ext_vector_type(2)));
typedef f32x4 __attribute__((aligned(4))) f32x4u;
typedef f32x2 __attribute__((aligned(4))) f32x2u;

__global__ __launch_bounds__(256) void rotation_kernel(
    const float* __restrict__ img,     // (H, W, 3) f32
    const float* __restrict__ fv,      // (1,) f32
    float* __restrict__ out)           // (H, W, 3) f32
{
    // ---- XCD-locality swizzle (bijective: NBLK % 8 == 0) ----
    // HW dispatches consecutive blockIdx round-robin across 8 XCDs.
    // Give XCD k the column-major range [k*CHUNK, (k+1)*CHUNK): 6 column
    // stripes traversed top-to-bottom, so same-XCD-consecutive blocks are
    // y-adjacent and share ~85% of their rotated source band in that L2.
    const unsigned D = blockIdx.x;
    const unsigned Lw = (D % NXCD) * CHUNK + (D / NXCD);  // column-major work id
    const int bx = Lw / GBY;
    const int by = Lw % GBY;

    const int c = bx * 64 + threadIdx.x;   // wave = 64 consecutive columns
    const int r = by * 4 + threadIdx.y;

    // theta in [0, 0.349] rad; HW trig absmax identical to libm (R5 evidence)
    const float theta = fv[0] * 20.0f * (3.14159265358979323846f / 180.0f);
    const float ct = __cosf(theta);
    const float st = __sinf(theta);

    const float o_r = (float)H_DIM / 2.0f + 0.5f;   // 1536.5
    const float o_c = (float)W_DIM / 2.0f + 0.5f;

    float src_r = ct * ((float)r - o_r) - st * ((float)c - o_c) + o_r;
    float src_c = st * ((float)r - o_r) + ct * ((float)c - o_c) + o_c;
    src_r = fminf(fmaxf(src_r, 0.0f), (float)(H_DIM - 1));
    src_c = fminf(fmaxf(src_c, 0.0f), (float)(W_DIM - 1));

    // Window-base trick: base = min(floor, dim-2), weight = src - base.
    // Interior: identical to reference. Clamped edge: weight == 1.0 exactly,
    // blend selects the far tap == edge pixel (matches fill_mode='nearest').
    const int rb = min((int)src_r, H_DIM - 2);
    const int cb = min((int)src_c, W_DIM - 2);
    const float wr = src_r - (float)rb;
    const float wc = src_c - (float)cb;

    const float* rp0 = img + (size_t)(rb * W_DIM + cb) * 3;
    const float* rp1 = rp0 + (size_t)W_DIM * 3;

    // 6 consecutive floats per tap row: x4 + x2 (minimum for interleaved RGB)
    const f32x4u A0 = *(const f32x4u*)rp0;
    const f32x2u B0 = *(const f32x2u*)(rp0 + 4);
    const f32x4u A1 = *(const f32x4u*)rp1;
    const f32x2u B1 = *(const f32x2u*)(rp1 + 4);

    const float q0[6] = {A0[0], A0[1], A0[2], A0[3], B0[0], B0[1]};
    const float q1[6] = {A1[0], A1[1], A1[2], A1[3], B1[0], B1[1]};

    float res[3];
    #pragma unroll
    for (int ch = 0; ch < 3; ++ch) {
        const float row0 = q0[ch] + wc * (q0[3 + ch] - q0[ch]);
        const float row1 = q1[ch] + wc * (q1[3 + ch] - q1[ch]);
        res[ch] = row0 + wr * (row1 - row0);
    }

    // 12B/px, wave-contiguous 768B
    float* o = out + ((size_t)r * W_DIM + c) * 3;
    o[0] = res[0];
    o[1] = res[1];
    o[2] = res[2];
}

extern "C" void kernel_launch(void* const* d_in, const int* in_sizes, int n_in,
                              void* d_out, int out_size, void* d_ws, size_t ws_size,
                              hipStream_t stream) {
    const float* img = (const float*)d_in[0];
    const float* fv  = (const float*)d_in[1];
    float* out = (float*)d_out;

    dim3 block(64, 4, 1);
    dim3 grid(NBLK, 1, 1);
    rotation_kernel<<<grid, block, 0, stream>>>(img, fv, out);
}